// Round 14
// baseline (262.800 us; speedup 1.0000x reference)
//
#include <hip/hip_runtime.h>
#include <hip/hip_bf16.h>

#define T_DIM 2048
#define N_DIM 256
#define K_DIM 256
#define C_DIM 40
#define CHUNK 32
#define NCHUNK 64                     // T_DIM / CHUNK
#define NTILES (T_DIM * N_DIM / 16)   // 32768 tiles of 16 rows

#define LOG2E_F 1.44269504088896340736f
#define LN2_F   0.69314718055994530942f
#define NEGBIG  (-1.0e30f)

typedef short bf16x8 __attribute__((ext_vector_type(8)));
typedef float f32x4  __attribute__((ext_vector_type(4)));

__device__ __forceinline__ float fexp2(float x) { return exp2f(x); }
__device__ __forceinline__ float flog2(float x) { return log2f(x); }
__device__ __forceinline__ float frcp(float x) { return __frcp_rn(x); }

__device__ __forceinline__ unsigned int pk2(float a, float b)
{
    __hip_bfloat162 h = __float22bfloat162_rn(make_float2(a, b));
    unsigned int r;
    __builtin_memcpy(&r, &h, sizeof(r));
    return r;
}

__device__ __forceinline__ uint4 pack8u(float4 lo, float4 hi)
{
    uint4 t;
    t.x = pk2(lo.x, lo.y);
    t.y = pk2(lo.z, lo.w);
    t.z = pk2(hi.x, hi.y);
    t.w = pk2(hi.z, hi.w);
    return t;
}

__device__ __forceinline__ bf16x8 as_bf16x8(uint4 u)
{
    bf16x8 r;
    __builtin_memcpy(&r, &u, sizeof(r));
    return r;
}

__device__ __forceinline__ unsigned short bf16r(float v)
{
    return (unsigned short)(pk2(v, 0.0f) & 0xffffu);
}

__device__ __forceinline__ float bl(unsigned int w) { return __uint_as_float(w << 16); }
__device__ __forceinline__ float bh(unsigned int w) { return __uint_as_float(w & 0xffff0000u); }

__device__ __forceinline__ float tanh5(float v)
{
    const float e = fexp2(fabsf(v) * (2.0f * LOG2E_F)); // e^(2|v|)
    const float t = 1.0f - 2.0f * frcp(e + 1.0f);       // tanh(|v|)
    return 5.0f * copysignf(t, v);
}

// ---------------------------------------------------------------------------
// K1: yb[row][c] = bf16(5*tanh(dot(x[row], W[c]) + b[c]))  via bf16 MFMA.
// Cross-round model (R5/R7/R9/R13/probe): streamed BW = waves/CU x
// outstanding-bytes/wave (~0.64 GB/s per 8KB-deep wave, cap ~5 TB/s).
// This version maximizes BOTH: 16 waves/CU (512thr, launch_bounds(512,4))
// AND 16KB in flight per wave - all 16 x-float4s of a tile loaded into an
// explicit lv[16] array (64 VGPR) BEFORE the pack/MFMA loop, with one
// sched_barrier(0) to stop the scheduler sinking loads into the consumers.
// Barrier-free main loop (waves fully independent, R7 shape); W as ready
// bf16 B-fragments in LDS (24 KB, canonical lane*16B = conflict-free
// b128); K-permuted mapping (R8) so each load instr is 64B-contiguous.
// ---------------------------------------------------------------------------
__global__ __launch_bounds__(512, 4) void k1_gemm_tanh(
    const float* __restrict__ x, const float* __restrict__ W,
    const float* __restrict__ b, unsigned short* __restrict__ yb)
{
    __shared__ __align__(16) uint4 wlds[24 * 64];   // 24 KB: frag = ks*3 + nt

    const int tid = threadIdx.x;

    // ---- cooperative W->fragment build (once per block), k-permuted ----
#pragma unroll
    for (int p = 0; p < 3; ++p) {
        const int f    = p * 512 + tid;   // 0..1535
        const int l    = f & 63;
        const int frag = f >> 6;          // 0..23
        const int nt   = frag % 3;
        const int ks   = frag / 3;
        const int col  = nt * 16 + (l & 15);
        const int kg   = l >> 4;
        float4 lo = make_float4(0, 0, 0, 0), hi = lo;
        if (col < C_DIM) {
            lo = *(const float4*)(W + (size_t)col * K_DIM + ks * 32 + kg * 4);
            hi = *(const float4*)(W + (size_t)col * K_DIM + ks * 32 + 16 + kg * 4);
        }
        wlds[frag * 64 + l] = pack8u(lo, hi);
    }
    __syncthreads();

    const int wave = tid >> 6;
    const int lane = tid & 63;
    const int lr   = lane & 15;   // A-row / B-col / D-col selector
    const int kg   = lane >> 4;   // k-group 0..3

    const float bc0 = b[lr];
    const float bc1 = b[16 + lr];
    const float bc2 = (lr < 8) ? b[32 + lr] : 0.0f;

    const int gw = blockIdx.x * 8 + wave;   // 0..4095; 8 tiles each, balanced

#pragma unroll 1
    for (int tile = gw; tile < NTILES; tile += 4096) {
        const float4* __restrict__ xp4 =
            (const float4*)(x + ((size_t)tile * 16 + lr) * K_DIM) + kg;

        // ---- load the lane's entire K-row: 16 float4 in flight (16 KB/wave)
        float4 lv[16];
#pragma unroll
        for (int i = 0; i < 8; ++i) {
            lv[2 * i]     = xp4[i * 8];       // x-cols i*32 + kg*4 ..+3
            lv[2 * i + 1] = xp4[i * 8 + 4];   // x-cols i*32+16+kg*4 ..+3
        }
        __builtin_amdgcn_sched_barrier(0);    // keep all loads issued first

        f32x4 af0 = {bc0, bc0, bc0, bc0};
        f32x4 af1 = {bc1, bc1, bc1, bc1};
        f32x4 af2 = {bc2, bc2, bc2, bc2};

#pragma unroll
        for (int ks = 0; ks < 8; ++ks) {
            const bf16x8 a  = as_bf16x8(pack8u(lv[2 * ks], lv[2 * ks + 1]));
            const bf16x8 w0 = *(const bf16x8*)&wlds[(ks * 3 + 0) * 64 + lane];
            const bf16x8 w1 = *(const bf16x8*)&wlds[(ks * 3 + 1) * 64 + lane];
            const bf16x8 w2 = *(const bf16x8*)&wlds[(ks * 3 + 2) * 64 + lane];
            af0 = __builtin_amdgcn_mfma_f32_16x16x32_bf16(a, w0, af0, 0, 0, 0);
            af1 = __builtin_amdgcn_mfma_f32_16x16x32_bf16(a, w1, af1, 0, 0, 0);
            af2 = __builtin_amdgcn_mfma_f32_16x16x32_bf16(a, w2, af2, 0, 0, 0);
        }

        // epilogue: D[row][col], row = kg*4+r, col = nt*16+lr
        unsigned short* yr = yb + ((size_t)tile * 16 + kg * 4) * C_DIM;
#pragma unroll
        for (int r = 0; r < 4; ++r) {
            yr[r * C_DIM + lr]      = bf16r(tanh5(af0[r]));
            yr[r * C_DIM + 16 + lr] = bf16r(tanh5(af1[r]));
            if (lr < 8)
                yr[r * C_DIM + 32 + lr] = bf16r(tanh5(af2[r]));
        }
    }
}

// ---------------------------------------------------------------------------
// K2: per (chain n, chunk g) propagate the 8x8 log-semiring matrix through
// 32 steps; y bf16 (5 x uint4 loads, shift-unpack). Base-2 domain.
// ---------------------------------------------------------------------------
__global__ __launch_bounds__(256) void k2_chunks(
    const unsigned short* __restrict__ yb, float* __restrict__ cmat)
{
    const int tid  = threadIdx.x;
    const int wave = tid >> 6;
    const int lane = tid & 63;
    const int task = lane >> 3;   // 8 tasks per wave
    const int c    = lane & 7;    // column owned by this lane
    const int g    = blockIdx.x & (NCHUNK - 1);
    const int n    = ((blockIdx.x >> 6) << 5) + (wave << 3) + task;

    float col[8];
#pragma unroll
    for (int j = 0; j < 8; ++j) col[j] = (j == c) ? 0.0f : NEGBIG;

    const unsigned short* __restrict__ yp =
        yb + ((size_t)(g * CHUNK) * N_DIM + (size_t)n) * C_DIM;

#pragma unroll 1
    for (int s = 0; s < CHUNK; ++s) {
        float sc[C_DIM];
        const uint4* p4 = (const uint4*)yp;
#pragma unroll
        for (int q = 0; q < 5; ++q) {
            const uint4 u = p4[q];
            sc[8 * q + 0] = bl(u.x) * LOG2E_F;
            sc[8 * q + 1] = bh(u.x) * LOG2E_F;
            sc[8 * q + 2] = bl(u.y) * LOG2E_F;
            sc[8 * q + 3] = bh(u.y) * LOG2E_F;
            sc[8 * q + 4] = bl(u.z) * LOG2E_F;
            sc[8 * q + 5] = bh(u.z) * LOG2E_F;
            sc[8 * q + 6] = bl(u.w) * LOG2E_F;
            sc[8 * q + 7] = bh(u.w) * LOG2E_F;
        }
        float nc[8];
#pragma unroll
        for (int d = 0; d < 4; ++d) {          // dense rows: lse over 8
            float tv[8];
#pragma unroll
            for (int j = 0; j < 8; ++j) tv[j] = sc[d * 8 + j] + col[j];
            float m = tv[0];
#pragma unroll
            for (int j = 1; j < 8; ++j) m = fmaxf(m, tv[j]);
            float ss = 0.0f;
#pragma unroll
            for (int j = 0; j < 8; ++j) ss += fexp2(tv[j] - m);
            nc[d] = m + flog2(ss);
        }
#pragma unroll
        for (int i = 0; i < 4; ++i) {          // sparse rows: logaddexp of 2
            const float a  = sc[32 + i] + col[i];
            const float bb = sc[36 + i] + col[i + 4];
            const float m  = fmaxf(a, bb);
            const float ss = fexp2(a - m) + fexp2(bb - m);
            nc[4 + i] = m + flog2(ss);
        }
#pragma unroll
        for (int j = 0; j < 8; ++j) col[j] = nc[j];
        yp += (size_t)N_DIM * C_DIM;
    }
    // store M[j][c] at cmat[((g*8 + c)*N_DIM + n)*8 + j]
    float* __restrict__ op = cmat + (((size_t)g * 8 + c) * N_DIM + n) * 8;
#pragma unroll
    for (int j = 0; j < 8; ++j) op[j] = col[j];
}

// ---------------------------------------------------------------------------
// K3: per chain, fold the 64 chunk matrices into logZ.
// ---------------------------------------------------------------------------
__global__ __launch_bounds__(256) void k3_combine(
    const float* __restrict__ cmat, float* __restrict__ corr)
{
    const int tid = threadIdx.x;
    const int d   = tid & 7;
    const int n   = blockIdx.x * 32 + (tid >> 3);

    float v[8];
#pragma unroll
    for (int j = 0; j < 8; ++j) v[j] = 0.0f;

#pragma unroll 1
    for (int g = 0; g < NCHUNK; ++g) {
        const float* mg = cmat + ((size_t)g * 8 * N_DIM + n) * 8 + d;
        float mm[8];
#pragma unroll
        for (int j = 0; j < 8; ++j) mm[j] = mg[(size_t)j * N_DIM * 8];
        float tv[8];
#pragma unroll
        for (int j = 0; j < 8; ++j) tv[j] = mm[j] + v[j];
        float m = tv[0];
#pragma unroll
        for (int j = 1; j < 8; ++j) m = fmaxf(m, tv[j]);
        float ss = 0.0f;
#pragma unroll
        for (int j = 0; j < 8; ++j) ss += fexp2(tv[j] - m);
        const float nv = m + flog2(ss);
#pragma unroll
        for (int j = 0; j < 8; ++j) v[j] = __shfl(nv, j, 8);
    }
    float m = v[0];
#pragma unroll
    for (int j = 1; j < 8; ++j) m = fmaxf(m, v[j]);
    float ss = 0.0f;
#pragma unroll
    for (int j = 0; j < 8; ++j) ss += fexp2(v[j] - m);
    const float lz2 = m + flog2(ss);                 // base-2 logZ
    if (d == 0) corr[n] = lz2 * LN2_F / (float)T_DIM;
}

// ---------------------------------------------------------------------------
// K4: out[t][n][c] = f32(yb[t][n][c]) - corr[n]
// ---------------------------------------------------------------------------
__global__ __launch_bounds__(256) void k4_final(
    const unsigned short* __restrict__ yb, const float* __restrict__ corr,
    float* __restrict__ out)
{
    const int i = blockIdx.x * 256 + threadIdx.x;    // 8-elem group index
    const uint4 u = ((const uint4*)yb)[i];
    const float cr = corr[(i / 5) & (N_DIM - 1)];    // 5 groups per row
    float4 o0, o1;
    o0.x = bl(u.x) - cr; o0.y = bh(u.x) - cr;
    o0.z = bl(u.y) - cr; o0.w = bh(u.y) - cr;
    o1.x = bl(u.z) - cr; o1.y = bh(u.z) - cr;
    o1.z = bl(u.w) - cr; o1.w = bh(u.w) - cr;
    float4* o4 = (float4*)out;
    o4[i * 2]     = o0;
    o4[i * 2 + 1] = o1;
}

// ---------------------------------------------------------------------------
extern "C" void kernel_launch(void* const* d_in, const int* in_sizes, int n_in,
                              void* d_out, int out_size, void* d_ws, size_t ws_size,
                              hipStream_t stream)
{
    const float* x = (const float*)d_in[0];
    const float* W = (const float*)d_in[1];
    const float* b = (const float*)d_in[2];
    float* out = (float*)d_out;

    unsigned short* ybf = (unsigned short*)d_ws;              // 40 MB bf16 y
    float* cmat = (float*)((char*)d_ws + (48u << 20));        // 4 MB
    float* corr = cmat + (size_t)NCHUNK * 8 * N_DIM * 8;

    hipLaunchKernelGGL(k1_gemm_tanh, dim3(512),  dim3(512), 0, stream, x, W, b, ybf);
    hipLaunchKernelGGL(k2_chunks,    dim3(512),  dim3(256), 0, stream, ybf, cmat);
    hipLaunchKernelGGL(k3_combine,   dim3(8),    dim3(256), 0, stream, cmat, corr);
    hipLaunchKernelGGL(k4_final,     dim3(T_DIM * N_DIM * C_DIM / 8 / 256),
                       dim3(256), 0, stream, ybf, corr, out);
}